// Round 2
// baseline (6831.408 us; speedup 1.0000x reference)
//
#include <hip/hip_runtime.h>
#include <stdint.h>

#define BATCHES 32
#define NPT     100000
#define NSAMP   1024
#define GPB     8          // blocks (groups) per batch
#define TPB     1024
#define PPB     12500      // points per block (8*12500 = 100000 exactly)
#define PPT     13         // points per thread (13*1024 = 13312 >= 12500)
#define NW      (TPB/64)   // waves per block = 16

typedef unsigned long long u64;
typedef unsigned int u32;

// ws layout:
//   seq  : u32 [BATCHES][GPB]            offset 0     size 1024 B
//   part : u64 [2][BATCHES][GPB][3]      offset 1024  size 12288 B
#define WS_SEQ_BYTES  (BATCHES*GPB*4)
#define WS_PART_BYTES (2*BATCHES*GPB*3*8)

// Reduce (key = f64 distance bits, idx, winner coords). Positive doubles
// compare monotonically as u64. Ties (exact equal dist) -> smaller index,
// matching np.argmax first-occurrence.
__device__ __forceinline__ void red_step(u64& key, u32& idx, float& x, float& y, float& z, int off) {
    u64   ok = __shfl_xor(key, off, 64);
    u32   oi = __shfl_xor(idx, off, 64);
    float ox = __shfl_xor(x, off, 64);
    float oy = __shfl_xor(y, off, 64);
    float oz = __shfl_xor(z, off, 64);
    if (ok > key || (ok == key && oi < idx)) { key = ok; idx = oi; x = ox; y = oy; z = oz; }
}

__launch_bounds__(TPB, 4)
__global__ void fps_kernel(const float* __restrict__ coord,
                           const int* __restrict__ seed_raw,
                           float* __restrict__ out,
                           u32* __restrict__ seq,
                           u64* __restrict__ part)
{
    const int tid  = threadIdx.x;
    const int lane = tid & 63;
    const int wid  = tid >> 6;
    const int b    = (int)blockIdx.x >> 3;
    const int g    = (int)blockIdx.x & 7;
    const int base = g * PPB;
    const float* cb = coord + (size_t)b * (NPT * 3);

    __shared__ u64   wkey[NW];
    __shared__ u32   widx[NW];
    __shared__ float wx[NW], wy[NW], wz[NW];
    __shared__ u32   s_win;
    __shared__ float s_cx, s_cy, s_cz;

    // Seed index. Robust to int32 or int64 materialization of farthest_init:
    // if int64 (little-endian), every odd 32-bit word (high half) is 0.
    int odd = 0;
    #pragma unroll
    for (int i = 1; i < 32; i += 2) odd |= seed_raw[i];
    int cur = (odd == 0) ? seed_raw[2 * b] : seed_raw[b];

    float cx = cb[(size_t)cur * 3 + 0];
    float cy = cb[(size_t)cur * 3 + 1];
    float cz = cb[(size_t)cur * 3 + 2];

    // Coords in f32 registers; running min-distance in f64 (matches a float64
    // numpy replication of the reference scan bitwise).
    float  px[PPT], py[PPT], pz[PPT];
    double d[PPT];
    #pragma unroll
    for (int k = 0; k < PPT; ++k) {
        int off = k * TPB + tid;
        bool v  = off < PPB;
        int gi  = base + (v ? off : 0);
        float x = cb[(size_t)gi * 3 + 0];
        float y = cb[(size_t)gi * 3 + 1];
        float z = cb[(size_t)gi * 3 + 2];
        px[k] = v ? x : 0.f;
        py[k] = v ? y : 0.f;
        pz[k] = v ? z : 0.f;
        d[k]  = v ? 1.0e10 : 0.0;   // fake points can never win argmax
    }

    float* cent_out = out;                       // (B, 1024) as float
    float* samp_out = out + BATCHES * NSAMP;     // (B, 1024, 3)

    for (int it = 0; it < NSAMP; ++it) {
        // Record current centroid (pre-update), as the reference does.
        if (g == 0 && tid == 0) {
            cent_out[b * NSAMP + it] = (float)cur;
            size_t so = ((size_t)b * NSAMP + it) * 3;
            samp_out[so + 0] = cx; samp_out[so + 1] = cy; samp_out[so + 2] = cz;
        }

        const double cxd = (double)cx, cyd = (double)cy, czd = (double)cz;

        // f64 distance update + per-thread argmax. Explicit _rn ops forbid
        // FMA contraction; sum order ((dx^2+dy^2)+dz^2) matches np.sum.
        double bd = -1.0; int bk = 0; float bx = 0.f, by = 0.f, bz = 0.f;
        #pragma unroll
        for (int k = 0; k < PPT; ++k) {
            double dx = __dsub_rn((double)px[k], cxd);
            double dy = __dsub_rn((double)py[k], cyd);
            double dz = __dsub_rn((double)pz[k], czd);
            double d2 = __dadd_rn(__dadd_rn(__dmul_rn(dx, dx), __dmul_rn(dy, dy)),
                                  __dmul_rn(dz, dz));
            double nd = fmin(d[k], d2);
            d[k] = nd;
            bool gt = nd > bd;       // strict > keeps smallest k (== smallest index)
            bd = gt ? nd : bd;
            bk = gt ? k : bk;
            bx = gt ? px[k] : bx;
            by = gt ? py[k] : by;
            bz = gt ? pz[k] : bz;
        }
        u32 gidx = (u32)(base + bk * TPB + tid);
        u64 key  = (u64)__double_as_longlong(bd);   // bd >= 0 -> monotone bits

        // Wave reduction (carry winning coords to avoid a serial global fetch).
        red_step(key, gidx, bx, by, bz, 32); red_step(key, gidx, bx, by, bz, 16);
        red_step(key, gidx, bx, by, bz, 8);  red_step(key, gidx, bx, by, bz, 4);
        red_step(key, gidx, bx, by, bz, 2);  red_step(key, gidx, bx, by, bz, 1);
        if (lane == 0) { wkey[wid] = key; widx[wid] = gidx; wx[wid] = bx; wy[wid] = by; wz[wid] = bz; }
        __syncthreads();

        if (wid == 0) {
            // Block-level reduce over 16 wave results (lanes 0..15).
            u64   k2 = (lane < NW) ? wkey[lane] : 0ull;
            u32   i2 = (lane < NW) ? widx[lane] : 0xFFFFFFFFu;
            float x2 = (lane < NW) ? wx[lane] : 0.f;
            float y2 = (lane < NW) ? wy[lane] : 0.f;
            float z2 = (lane < NW) ? wz[lane] : 0.f;
            red_step(k2, i2, x2, y2, z2, 8); red_step(k2, i2, x2, y2, z2, 4);
            red_step(k2, i2, x2, y2, z2, 2); red_step(k2, i2, x2, y2, z2, 1);

            const int par = it & 1;   // parity double-buffer for partials
            if (lane == 0) {
                u64* rec = part + ((size_t)((par * BATCHES + b) * GPB + g)) * 3;
                __hip_atomic_store(&rec[0], k2, __ATOMIC_RELAXED, __HIP_MEMORY_SCOPE_AGENT);
                u64 xy = ((u64)__float_as_uint(y2) << 32) | __float_as_uint(x2);
                __hip_atomic_store(&rec[1], xy, __ATOMIC_RELAXED, __HIP_MEMORY_SCOPE_AGENT);
                u64 zi = ((u64)i2 << 32) | __float_as_uint(z2);
                __hip_atomic_store(&rec[2], zi, __ATOMIC_RELAXED, __HIP_MEMORY_SCOPE_AGENT);
                __hip_atomic_store(&seq[b * GPB + g], (u32)(it + 1), __ATOMIC_RELEASE, __HIP_MEMORY_SCOPE_AGENT);
            }
            // Spin until all 8 blocks of this batch posted iteration it.
            const u32 target = (u32)(it + 1);
            for (;;) {
                u32 s = (lane < GPB)
                    ? __hip_atomic_load(&seq[b * GPB + lane], __ATOMIC_ACQUIRE, __HIP_MEMORY_SCOPE_AGENT)
                    : target;
                if (__ballot(s >= target) == ~0ull) break;
                __builtin_amdgcn_s_sleep(1);
            }
            // Read the 8 partials, reduce redundantly (deterministic).
            u64 k3 = 0ull; u32 i3 = 0xFFFFFFFFu; float x3 = 0.f, y3 = 0.f, z3 = 0.f;
            if (lane < GPB) {
                const u64* rec = part + ((size_t)((par * BATCHES + b) * GPB + lane)) * 3;
                k3 = __hip_atomic_load(&rec[0], __ATOMIC_RELAXED, __HIP_MEMORY_SCOPE_AGENT);
                u64 xy = __hip_atomic_load(&rec[1], __ATOMIC_RELAXED, __HIP_MEMORY_SCOPE_AGENT);
                u64 zi = __hip_atomic_load(&rec[2], __ATOMIC_RELAXED, __HIP_MEMORY_SCOPE_AGENT);
                x3 = __uint_as_float((u32)xy);
                y3 = __uint_as_float((u32)(xy >> 32));
                z3 = __uint_as_float((u32)zi);
                i3 = (u32)(zi >> 32);
            }
            red_step(k3, i3, x3, y3, z3, 4); red_step(k3, i3, x3, y3, z3, 2); red_step(k3, i3, x3, y3, z3, 1);
            if (lane == 0) {
                s_win = i3;
                s_cx = x3; s_cy = y3; s_cz = z3;
            }
        }
        __syncthreads();
        cur = (int)s_win; cx = s_cx; cy = s_cy; cz = s_cz;
    }
}

extern "C" void kernel_launch(void* const* d_in, const int* in_sizes, int n_in,
                              void* d_out, int out_size, void* d_ws, size_t ws_size,
                              hipStream_t stream)
{
    const float* coord = (const float*)d_in[0];
    const int*   seed  = (const int*)d_in[1];
    float* out = (float*)d_out;
    u32* seq = (u32*)d_ws;
    u64* part = (u64*)((char*)d_ws + WS_SEQ_BYTES);

    hipMemsetAsync(d_ws, 0, WS_SEQ_BYTES + WS_PART_BYTES, stream);
    fps_kernel<<<dim3(BATCHES * GPB), dim3(TPB), 0, stream>>>(coord, seed, out, seq, part);
}